// Round 7
// baseline (98.021 us; speedup 1.0000x reference)
//
#include <hip/hip_runtime.h>

// Sizes (fixed by the reference)
#define NN 32
#define CC 64
#define TT 300
#define VV 25
#define KK 3
#define OO 64
#define TB 4          // time steps per block
#define SB (TB * VV)  // 100 output spatial positions per block
#define NREP 64       // replicated stats accumulators

// ws layout (floats):
//  [0..128)         final stats (sum, sumsq per channel)
//  [128..8320)      replica accumulators NREP*128
//  [8320..14464)    Wpk: 1536 short8 W-fragments (24 KB)
//  [14464..16000)   Apk: 384 short8 A-fragments (6 KB)
#define REP_OFF 128
#define WPK_OFF 8320
#define APK_OFF 14464

typedef __attribute__((ext_vector_type(8))) short short8;  // 8 bf16 = 4 VGPR
typedef __attribute__((ext_vector_type(4))) float f32x4;

// f32 -> bf16, round-to-nearest-even
__device__ __forceinline__ unsigned short f2bf(float f) {
    unsigned u = __builtin_bit_cast(unsigned, f);
    u += 0x7FFFu + ((u >> 16) & 1u);
    return (unsigned short)(u >> 16);
}

// One-time: zero stats+replicas, pack W and A into exact MFMA fragment layout.
__global__ __launch_bounds__(512) void prep_pack(const float* __restrict__ A,
                                                 const float* __restrict__ W,
                                                 float* __restrict__ ws) {
    const int i = blockIdx.x * 512 + threadIdx.x;  // grid 4 -> 2048 threads
    for (int j = i; j < REP_OFF + NREP * 128; j += 2048) ws[j] = 0.0f;
    unsigned short* Wpk = reinterpret_cast<unsigned short*>(ws + WPK_OFF);
    unsigned short* Apk = reinterpret_cast<unsigned short*>(ws + APK_OFF);
    if (i < 1536) {
        // Wpk[mt][kap][lane]: A-operand frag, row o = mt*16+li, k-elems = kap*32+g*8+e
        int mt = i / 384, r = i - mt * 384;
        int kap = r / 64, lane = r - kap * 64;
        int li = lane & 15, g = lane >> 4;
        int o  = mt * 16 + li;
        int k  = kap >> 1, c0 = (kap & 1) * 32 + g * 8;
        const float* wp = W + ((size_t)(k * OO + o)) * CC + c0;
#pragma unroll
        for (int e = 0; e < 8; ++e) Wpk[i * 8 + e] = f2bf(wp[e]);
    } else if (i < 1920) {
        // Apk[k*2+nt][lane]: B-operand frag (A^T), col w = nt*16+li, k-elems v = g*8+e
        int j = i - 1536;
        int k = j / 128, r = j - k * 128;
        int nt = r / 64, lane = r - nt * 64;
        int li = lane & 15, g = lane >> 4;
        int w = nt * 16 + li;
#pragma unroll
        for (int e = 0; e < 8; ++e) {
            int v = g * 8 + e;
            float val = (v < VV && w < VV) ? A[(k * VV + v) * VV + w] : 0.0f;
            Apk[j * 8 + e] = f2bf(val);
        }
    }
}

// Block: (n, 4 time steps), 512 threads = 8 waves. K-sliced pipeline:
//  Phase A: stage x -> bf16 x_s[row=t*64+c][v pad32]   (16 KB)
//  per k: Phase B_k: GEMM1 slice -> xa_s[s][c 64]      (14 KB, reused 3x)
//         Phase C_k: GEMM2 partial K=64 -> yac (regs)
//  Epilogue: stores + per-channel stats (shfl reduce -> LDS -> replicated atomics)
__global__ __launch_bounds__(512, 8) void gcn_main(const float* __restrict__ x,
                                                   const float* __restrict__ ws,
                                                   float* __restrict__ ypre) {
    __shared__ alignas(16) unsigned short x_s[256 * 32];   // 16 KB
    __shared__ alignas(16) unsigned short xa_s[112 * 64];  // 14 KB (rows 100..111 pad,
                                                           // feed masked-out C cols only)
    __shared__ float stats_s[128];

    const int bid  = blockIdx.x;
    const int n    = bid / (TT / TB);
    const int t0   = (bid % (TT / TB)) * TB;
    const int tid  = threadIdx.x;
    const int lane = tid & 63;
    const int wid  = tid >> 6;
    const int li   = lane & 15;   // fragment row/col index
    const int g    = lane >> 4;   // 16-lane group: k-elems = 8g..8g+7

    const short8* Wpk = reinterpret_cast<const short8*>(ws + WPK_OFF);
    const short8* Apk = reinterpret_cast<const short8*>(ws + APK_OFF);

    if (tid < 128) stats_s[tid] = 0.0f;

    // ---- Phase A: stage x (coalesced float4 global, scalar bf16 LDS writes)
    const float* xg = x + (size_t)n * (CC * TT * VV) + (size_t)t0 * VV;
    for (int idx = tid; idx < CC * 25; idx += 512) {  // 1600 float4
        int c = idx / 25, q = idx - c * 25;
        const float4 f = *reinterpret_cast<const float4*>(xg + (size_t)c * (TT * VV) + q * 4);
        float vals[4] = {f.x, f.y, f.z, f.w};
        int s0 = q * 4;
#pragma unroll
        for (int i = 0; i < 4; ++i) {
            int sp = s0 + i;               // may straddle the 25-joint boundary
            int t = sp / 25, v = sp - t * 25;
            int row = t * 64 + c;
            x_s[row * 32 + (v ^ (((row >> 1) & 3) << 3))] = f2bf(vals[i]);
        }
    }
    for (int idx = tid; idx < 256 * 7; idx += 512) {  // zero-fill K-pad v=25..31
        int row = idx / 7, v = 25 + (idx - row * 7);
        x_s[row * 32 + (v ^ (((row >> 1) & 3) << 3))] = 0;
    }
    __syncthreads();

    f32x4 yac[4] = {{0.f,0.f,0.f,0.f},{0.f,0.f,0.f,0.f},{0.f,0.f,0.f,0.f},{0.f,0.f,0.f,0.f}};

    // ---- K-sliced B/C: xa slice is 64 kc-columns (one adjacency branch k)
#pragma unroll
    for (int k = 0; k < KK; ++k) {
        // afrag loaded per-slice (2 coalesced 16B loads; keeps live VGPRs low)
        const short8 af0 = Apk[(k * 2 + 0) * 64 + lane];
        const short8 af1 = Apk[(k * 2 + 1) * 64 + lane];

        // Phase B_k: M=(t*64+c) 256 rows = 16 Mtiles, N=w (2 tiles), K=32
        for (int mt = wid; mt < 16; mt += 8) {
            int row = mt * 16 + li;
            const short8 xf = *reinterpret_cast<const short8*>(
                &x_s[row * 32 + ((g * 8) ^ (((row >> 1) & 3) << 3))]);
            f32x4 a0 = {0.f,0.f,0.f,0.f}, a1 = {0.f,0.f,0.f,0.f};
            a0 = __builtin_amdgcn_mfma_f32_16x16x32_bf16(xf, af0, a0, 0, 0, 0);
            a1 = __builtin_amdgcn_mfma_f32_16x16x32_bf16(xf, af1, a1, 0, 0, 0);
            // C-frag: col=li (w), rows = mt*16+4g+j -> t = row>>6, c-quad = row&63
            int r0 = mt * 16 + g * 4;
            int t = r0 >> 6, c0 = r0 & 63;
            {
                int s = t * 25 + li;
                unsigned long long p =
                    (unsigned long long)f2bf(a0[0]) |
                    ((unsigned long long)f2bf(a0[1]) << 16) |
                    ((unsigned long long)f2bf(a0[2]) << 32) |
                    ((unsigned long long)f2bf(a0[3]) << 48);
                *reinterpret_cast<unsigned long long*>(
                    &xa_s[s * 64 + (c0 ^ ((s & 7) << 3))]) = p;
            }
            int w1 = 16 + li;
            if (w1 < VV) {
                int s = t * 25 + w1;
                unsigned long long p =
                    (unsigned long long)f2bf(a1[0]) |
                    ((unsigned long long)f2bf(a1[1]) << 16) |
                    ((unsigned long long)f2bf(a1[2]) << 32) |
                    ((unsigned long long)f2bf(a1[3]) << 48);
                *reinterpret_cast<unsigned long long*>(
                    &xa_s[s * 64 + (c0 ^ ((s & 7) << 3))]) = p;
            }
        }
        __syncthreads();

        // Phase C_k: M=o (4 Mtiles), N=s (7 Ntiles), K=64 (2 MFMA), accumulate yac
#pragma unroll
        for (int i = 0; i < 4; ++i) {
            int u = wid + 8 * i;          // wave-uniform; waves 4..7 skip i=3
            if (u < 28) {
                int mt = u / 7, nt = u - mt * 7;
                int srow = nt * 16 + li;
                const short8* wb = Wpk + (size_t)(mt * 6 + 2 * k) * 64 + lane;
                const short8 wf0 = wb[0];
                const short8 wf1 = wb[64];
                const short8 xa0 = *reinterpret_cast<const short8*>(
                    &xa_s[srow * 64 + ((g * 8) ^ ((srow & 7) << 3))]);
                const short8 xa1 = *reinterpret_cast<const short8*>(
                    &xa_s[srow * 64 + ((32 + g * 8) ^ ((srow & 7) << 3))]);
                yac[i] = __builtin_amdgcn_mfma_f32_16x16x32_bf16(wf0, xa0, yac[i], 0, 0, 0);
                yac[i] = __builtin_amdgcn_mfma_f32_16x16x32_bf16(wf1, xa1, yac[i], 0, 0, 0);
            }
        }
        if (k < KK - 1) __syncthreads();  // protect xa_s before next B-slice overwrites
    }

    // ---- Epilogue: stores + stats. C-frag col = srow (s), rows = oq..oq+3
#pragma unroll
    for (int i = 0; i < 4; ++i) {
        int u = wid + 8 * i;
        if (u < 28) {
            int mt = u / 7, nt = u - mt * 7;
            int srow = nt * 16 + li;
            bool sv = srow < SB;
            int oq = mt * 16 + g * 4;
            if (sv) {
                size_t base = ((size_t)n * OO + oq) * (TT * VV) + (size_t)t0 * VV + srow;
                ypre[base              ] = yac[i][0];
                ypre[base + 1 * TT * VV] = yac[i][1];
                ypre[base + 2 * TT * VV] = yac[i][2];
                ypre[base + 3 * TT * VV] = yac[i][3];
            }
            float s1[4], s2[4];
#pragma unroll
            for (int j = 0; j < 4; ++j) {
                float v = sv ? yac[i][j] : 0.0f;
                s1[j] = v;
                s2[j] = v * v;
            }
#pragma unroll
            for (int d = 1; d < 16; d <<= 1) {
#pragma unroll
                for (int j = 0; j < 4; ++j) {
                    s1[j] += __shfl_xor(s1[j], d);
                    s2[j] += __shfl_xor(s2[j], d);
                }
            }
            if (li == 0) {
#pragma unroll
                for (int j = 0; j < 4; ++j) {
                    atomicAdd(&stats_s[oq + j], s1[j]);
                    atomicAdd(&stats_s[64 + oq + j], s2[j]);
                }
            }
        }
    }
    // NOTE: per-branch bias b.sum(0) is a per-channel constant -> exactly
    // cancelled by training-mode BN. Skipped on purpose (exact).
    __syncthreads();
    if (tid < 128)
        atomicAdd(&((float*)ws)[REP_OFF + (bid & (NREP - 1)) * 128 + tid], stats_s[tid]);
}

// Fold NREP replicas -> final stats at ws[0..128)
__global__ __launch_bounds__(128) void reduce_stats(float* ws) {
    const int t = threadIdx.x;
    float s = 0.0f;
#pragma unroll 8
    for (int r = 0; r < NREP; ++r) s += ws[REP_OFF + r * 128 + t];
    ws[t] = s;
}

__global__ __launch_bounds__(256) void bn_relu(float* __restrict__ y,
                                               const float* __restrict__ stats,
                                               const float* __restrict__ gamma,
                                               const float* __restrict__ beta) {
    const int i4 = blockIdx.x * 256 + threadIdx.x;
    const size_t i = (size_t)i4 * 4;
    const int o = (int)((i / (TT * VV)) % OO);  // TT*VV=7500 divisible by 4

    const float cnt  = (float)NN * TT * VV;
    const float mean = stats[o] / cnt;
    const float var  = stats[OO + o] / cnt - mean * mean;
    const float inv  = rsqrtf(var + 1e-5f);
    const float sc   = gamma[o] * inv;
    const float sh   = beta[o] - mean * sc;

    float4 v = *reinterpret_cast<float4*>(y + i);
    v.x = fmaxf(v.x * sc + sh, 0.0f);
    v.y = fmaxf(v.y * sc + sh, 0.0f);
    v.z = fmaxf(v.z * sc + sh, 0.0f);
    v.w = fmaxf(v.w * sc + sh, 0.0f);
    *reinterpret_cast<float4*>(y + i) = v;
}

extern "C" void kernel_launch(void* const* d_in, const int* in_sizes, int n_in,
                              void* d_out, int out_size, void* d_ws, size_t ws_size,
                              hipStream_t stream) {
    const float* x     = (const float*)d_in[0];
    const float* A     = (const float*)d_in[1];
    const float* W     = (const float*)d_in[2];
    // d_in[3] = b : exactly cancelled by training-mode BN, unused
    const float* gamma = (const float*)d_in[4];
    const float* beta  = (const float*)d_in[5];
    float* out = (float*)d_out;
    float* ws  = (float*)d_ws;  // 64 KB used, layout at top

    hipLaunchKernelGGL(prep_pack, dim3(4), dim3(512), 0, stream, A, W, ws);
    hipLaunchKernelGGL(gcn_main, dim3(NN * (TT / TB)), dim3(512), 0, stream,
                       x, ws, out);
    hipLaunchKernelGGL(reduce_stats, dim3(1), dim3(128), 0, stream, ws);
    hipLaunchKernelGGL(bn_relu, dim3((NN * OO * TT * VV) / 4 / 256), dim3(256), 0, stream,
                       out, ws, gamma, beta);
}

// Round 8
// 93.486 us; speedup vs baseline: 1.0485x; 1.0485x over previous
//
#include <hip/hip_runtime.h>

// Sizes (fixed by the reference)
#define NN 32
#define CC 64
#define TT 300
#define VV 25
#define KK 3
#define OO 64
#define TB 4          // time steps per block
#define SB (TB * VV)  // 100 output spatial positions per block
#define NREP 64       // replicated stats accumulators

// ws layout (floats):
//  [0..128)         final stats (sum, sumsq per channel)
//  [128..8320)      replica accumulators NREP*128
//  [8320..14464)    Wpk: 1536 short8 W-fragments (24 KB)
//  [14464..16000)   Apk: 384 short8 A-fragments (6 KB)
#define REP_OFF 128
#define WPK_OFF 8320
#define APK_OFF 14464

typedef __attribute__((ext_vector_type(8))) short short8;  // 8 bf16 = 4 VGPR
typedef __attribute__((ext_vector_type(4))) float f32x4;

// f32 -> bf16, round-to-nearest-even
__device__ __forceinline__ unsigned short f2bf(float f) {
    unsigned u = __builtin_bit_cast(unsigned, f);
    u += 0x7FFFu + ((u >> 16) & 1u);
    return (unsigned short)(u >> 16);
}

// One-time: zero stats+replicas, pack W and A into exact MFMA fragment layout.
__global__ __launch_bounds__(512) void prep_pack(const float* __restrict__ A,
                                                 const float* __restrict__ W,
                                                 float* __restrict__ ws) {
    const int i = blockIdx.x * 512 + threadIdx.x;  // grid 4 -> 2048 threads
    for (int j = i; j < REP_OFF + NREP * 128; j += 2048) ws[j] = 0.0f;
    unsigned short* Wpk = reinterpret_cast<unsigned short*>(ws + WPK_OFF);
    unsigned short* Apk = reinterpret_cast<unsigned short*>(ws + APK_OFF);
    if (i < 1536) {
        // Wpk[mt][kap][lane]: A-operand frag, row o = mt*16+li, k-elems = kap*32+g*8+e
        int mt = i / 384, r = i - mt * 384;
        int kap = r / 64, lane = r - kap * 64;
        int li = lane & 15, g = lane >> 4;
        int o  = mt * 16 + li;
        int k  = kap >> 1, c0 = (kap & 1) * 32 + g * 8;
        const float* wp = W + ((size_t)(k * OO + o)) * CC + c0;
#pragma unroll
        for (int e = 0; e < 8; ++e) Wpk[i * 8 + e] = f2bf(wp[e]);
    } else if (i < 1920) {
        // Apk[k*2+nt][lane]: B-operand frag (A^T), col w = nt*16+li, k-elems v = g*8+e
        int j = i - 1536;
        int k = j / 128, r = j - k * 128;
        int nt = r / 64, lane = r - nt * 64;
        int li = lane & 15, g = lane >> 4;
        int w = nt * 16 + li;
#pragma unroll
        for (int e = 0; e < 8; ++e) {
            int v = g * 8 + e;
            float val = (v < VV && w < VV) ? A[(k * VV + v) * VV + w] : 0.0f;
            Apk[j * 8 + e] = f2bf(val);
        }
    }
}

// Block: (n, 4 time steps), 512 threads = 8 waves. K-sliced pipeline:
//  Phase A: stage x -> bf16 x_s[row=t*64+c][v pad32]   (16 KB)
//  per k: Phase B_k: GEMM1 slice -> xa_s[s][c 64]      (14 KB, reused 3x)
//         Phase C_k: GEMM2 partial K=64 -> yac (regs)
//  Epilogue: stores + per-channel stats (shfl reduce -> LDS -> replicated atomics)
// launch_bounds(512,6): VGPR cap ~85 >> natural ~60 -> NO SPILLS (R7's (512,8)
// forced <=64 and spilled yac to scratch: WRITE_SIZE doubled, 84us regression).
__global__ __launch_bounds__(512, 6) void gcn_main(const float* __restrict__ x,
                                                   const float* __restrict__ ws,
                                                   float* __restrict__ ypre) {
    __shared__ alignas(16) unsigned short x_s[256 * 32];   // 16 KB
    __shared__ alignas(16) unsigned short xa_s[112 * 64];  // 14 KB (rows 100..111 pad,
                                                           // feed masked-out C cols only)
    __shared__ float stats_s[128];

    const int bid  = blockIdx.x;
    const int n    = bid / (TT / TB);
    const int t0   = (bid % (TT / TB)) * TB;
    const int tid  = threadIdx.x;
    const int lane = tid & 63;
    const int wid  = tid >> 6;
    const int li   = lane & 15;   // fragment row/col index
    const int g    = lane >> 4;   // 16-lane group: k-elems = 8g..8g+7

    const short8* Wpk = reinterpret_cast<const short8*>(ws + WPK_OFF);
    const short8* Apk = reinterpret_cast<const short8*>(ws + APK_OFF);

    if (tid < 128) stats_s[tid] = 0.0f;

    // ---- Phase A: stage x (coalesced float4 global, scalar bf16 LDS writes)
    const float* xg = x + (size_t)n * (CC * TT * VV) + (size_t)t0 * VV;
    for (int idx = tid; idx < CC * 25; idx += 512) {  // 1600 float4
        int c = idx / 25, q = idx - c * 25;
        const float4 f = *reinterpret_cast<const float4*>(xg + (size_t)c * (TT * VV) + q * 4);
        float vals[4] = {f.x, f.y, f.z, f.w};
        int s0 = q * 4;
#pragma unroll
        for (int i = 0; i < 4; ++i) {
            int sp = s0 + i;               // may straddle the 25-joint boundary
            int t = sp / 25, v = sp - t * 25;
            int row = t * 64 + c;
            x_s[row * 32 + (v ^ (((row >> 1) & 3) << 3))] = f2bf(vals[i]);
        }
    }
    for (int idx = tid; idx < 256 * 7; idx += 512) {  // zero-fill K-pad v=25..31
        int row = idx / 7, v = 25 + (idx - row * 7);
        x_s[row * 32 + (v ^ (((row >> 1) & 3) << 3))] = 0;
    }
    __syncthreads();

    f32x4 yac[4] = {{0.f,0.f,0.f,0.f},{0.f,0.f,0.f,0.f},{0.f,0.f,0.f,0.f},{0.f,0.f,0.f,0.f}};

    // ---- K-sliced B/C: xa slice is 64 kc-columns (one adjacency branch k)
#pragma unroll
    for (int k = 0; k < KK; ++k) {
        // afrag loaded per-slice (2 coalesced 16B loads; keeps live VGPRs low)
        const short8 af0 = Apk[(k * 2 + 0) * 64 + lane];
        const short8 af1 = Apk[(k * 2 + 1) * 64 + lane];

        // Phase B_k: M=(t*64+c) 256 rows = 16 Mtiles, N=w (2 tiles), K=32
        for (int mt = wid; mt < 16; mt += 8) {
            int row = mt * 16 + li;
            const short8 xf = *reinterpret_cast<const short8*>(
                &x_s[row * 32 + ((g * 8) ^ (((row >> 1) & 3) << 3))]);
            f32x4 a0 = {0.f,0.f,0.f,0.f}, a1 = {0.f,0.f,0.f,0.f};
            a0 = __builtin_amdgcn_mfma_f32_16x16x32_bf16(xf, af0, a0, 0, 0, 0);
            a1 = __builtin_amdgcn_mfma_f32_16x16x32_bf16(xf, af1, a1, 0, 0, 0);
            // C-frag: col=li (w), rows = mt*16+4g+j -> t = row>>6, c-quad = row&63
            int r0 = mt * 16 + g * 4;
            int t = r0 >> 6, c0 = r0 & 63;
            {
                int s = t * 25 + li;
                unsigned long long p =
                    (unsigned long long)f2bf(a0[0]) |
                    ((unsigned long long)f2bf(a0[1]) << 16) |
                    ((unsigned long long)f2bf(a0[2]) << 32) |
                    ((unsigned long long)f2bf(a0[3]) << 48);
                *reinterpret_cast<unsigned long long*>(
                    &xa_s[s * 64 + (c0 ^ ((s & 7) << 3))]) = p;
            }
            int w1 = 16 + li;
            if (w1 < VV) {
                int s = t * 25 + w1;
                unsigned long long p =
                    (unsigned long long)f2bf(a1[0]) |
                    ((unsigned long long)f2bf(a1[1]) << 16) |
                    ((unsigned long long)f2bf(a1[2]) << 32) |
                    ((unsigned long long)f2bf(a1[3]) << 48);
                *reinterpret_cast<unsigned long long*>(
                    &xa_s[s * 64 + (c0 ^ ((s & 7) << 3))]) = p;
            }
        }
        __syncthreads();

        // Phase C_k: M=o (4 Mtiles), N=s (7 Ntiles), K=64 (2 MFMA), accumulate yac
#pragma unroll
        for (int i = 0; i < 4; ++i) {
            int u = wid + 8 * i;          // wave-uniform; waves 4..7 skip i=3
            if (u < 28) {
                int mt = u / 7, nt = u - mt * 7;
                int srow = nt * 16 + li;
                const short8* wb = Wpk + (size_t)(mt * 6 + 2 * k) * 64 + lane;
                const short8 wf0 = wb[0];
                const short8 wf1 = wb[64];
                const short8 xa0 = *reinterpret_cast<const short8*>(
                    &xa_s[srow * 64 + ((g * 8) ^ ((srow & 7) << 3))]);
                const short8 xa1 = *reinterpret_cast<const short8*>(
                    &xa_s[srow * 64 + ((32 + g * 8) ^ ((srow & 7) << 3))]);
                yac[i] = __builtin_amdgcn_mfma_f32_16x16x32_bf16(wf0, xa0, yac[i], 0, 0, 0);
                yac[i] = __builtin_amdgcn_mfma_f32_16x16x32_bf16(wf1, xa1, yac[i], 0, 0, 0);
            }
        }
        if (k < KK - 1) __syncthreads();  // protect xa_s before next B-slice overwrites
    }

    // ---- Epilogue: stores + stats. C-frag col = srow (s), rows = oq..oq+3
#pragma unroll
    for (int i = 0; i < 4; ++i) {
        int u = wid + 8 * i;
        if (u < 28) {
            int mt = u / 7, nt = u - mt * 7;
            int srow = nt * 16 + li;
            bool sv = srow < SB;
            int oq = mt * 16 + g * 4;
            if (sv) {
                size_t base = ((size_t)n * OO + oq) * (TT * VV) + (size_t)t0 * VV + srow;
                ypre[base              ] = yac[i][0];
                ypre[base + 1 * TT * VV] = yac[i][1];
                ypre[base + 2 * TT * VV] = yac[i][2];
                ypre[base + 3 * TT * VV] = yac[i][3];
            }
            float s1[4], s2[4];
#pragma unroll
            for (int j = 0; j < 4; ++j) {
                float v = sv ? yac[i][j] : 0.0f;
                s1[j] = v;
                s2[j] = v * v;
            }
#pragma unroll
            for (int d = 1; d < 16; d <<= 1) {
#pragma unroll
                for (int j = 0; j < 4; ++j) {
                    s1[j] += __shfl_xor(s1[j], d);
                    s2[j] += __shfl_xor(s2[j], d);
                }
            }
            if (li == 0) {
#pragma unroll
                for (int j = 0; j < 4; ++j) {
                    atomicAdd(&stats_s[oq + j], s1[j]);
                    atomicAdd(&stats_s[64 + oq + j], s2[j]);
                }
            }
        }
    }
    // NOTE: per-branch bias b.sum(0) is a per-channel constant -> exactly
    // cancelled by training-mode BN. Skipped on purpose (exact).
    __syncthreads();
    if (tid < 128)
        atomicAdd(&((float*)ws)[REP_OFF + (bid & (NREP - 1)) * 128 + tid], stats_s[tid]);
}

// Fold NREP replicas -> final stats at ws[0..128)
__global__ __launch_bounds__(128) void reduce_stats(float* ws) {
    const int t = threadIdx.x;
    float s = 0.0f;
#pragma unroll 8
    for (int r = 0; r < NREP; ++r) s += ws[REP_OFF + r * 128 + t];
    ws[t] = s;
}

__global__ __launch_bounds__(256) void bn_relu(float* __restrict__ y,
                                               const float* __restrict__ stats,
                                               const float* __restrict__ gamma,
                                               const float* __restrict__ beta) {
    const int i4 = blockIdx.x * 256 + threadIdx.x;
    const size_t i = (size_t)i4 * 4;
    const int o = (int)((i / (TT * VV)) % OO);  // TT*VV=7500 divisible by 4

    const float cnt  = (float)NN * TT * VV;
    const float mean = stats[o] / cnt;
    const float var  = stats[OO + o] / cnt - mean * mean;
    const float inv  = rsqrtf(var + 1e-5f);
    const float sc   = gamma[o] * inv;
    const float sh   = beta[o] - mean * sc;

    float4 v = *reinterpret_cast<float4*>(y + i);
    v.x = fmaxf(v.x * sc + sh, 0.0f);
    v.y = fmaxf(v.y * sc + sh, 0.0f);
    v.z = fmaxf(v.z * sc + sh, 0.0f);
    v.w = fmaxf(v.w * sc + sh, 0.0f);
    *reinterpret_cast<float4*>(y + i) = v;
}

extern "C" void kernel_launch(void* const* d_in, const int* in_sizes, int n_in,
                              void* d_out, int out_size, void* d_ws, size_t ws_size,
                              hipStream_t stream) {
    const float* x     = (const float*)d_in[0];
    const float* A     = (const float*)d_in[1];
    const float* W     = (const float*)d_in[2];
    // d_in[3] = b : exactly cancelled by training-mode BN, unused
    const float* gamma = (const float*)d_in[4];
    const float* beta  = (const float*)d_in[5];
    float* out = (float*)d_out;
    float* ws  = (float*)d_ws;  // 64 KB used, layout at top

    hipLaunchKernelGGL(prep_pack, dim3(4), dim3(512), 0, stream, A, W, ws);
    hipLaunchKernelGGL(gcn_main, dim3(NN * (TT / TB)), dim3(512), 0, stream,
                       x, ws, out);
    hipLaunchKernelGGL(reduce_stats, dim3(1), dim3(128), 0, stream, ws);
    hipLaunchKernelGGL(bn_relu, dim3((NN * OO * TT * VV) / 4 / 256), dim3(256), 0, stream,
                       out, ws, gamma, beta);
}

// Round 9
// 87.880 us; speedup vs baseline: 1.1154x; 1.0638x over previous
//
#include <hip/hip_runtime.h>

// Sizes (fixed by the reference)
#define NN 32
#define CC 64
#define TT 300
#define VV 25
#define KK 3
#define OO 64
#define TB 2          // time steps per block
#define SB (TB * VV)  // 50 output spatial positions per block
#define NREP 64       // replicated stats accumulators

// ws layout (floats):
//  [0..128)         final stats (sum, sumsq per channel)
//  [128..8320)      replica accumulators NREP*128
//  [8320..14464)    Wpk: 1536 short8 W-fragments (24 KB)
//  [14464..16000)   Apk: 384 short8 A-fragments (6 KB)
//  [16384.. )       optional bf16 y buffer (30.72 MB) if ws_size permits
#define REP_OFF 128
#define WPK_OFF 8320
#define APK_OFF 14464
#define YBF_OFF 16384
#define YBF_BYTES ((size_t)NN * OO * TT * VV * 2)
#define WS_NEED_BF16 ((size_t)YBF_OFF * 4 + YBF_BYTES)

typedef __attribute__((ext_vector_type(8))) short short8;  // 8 bf16 = 4 VGPR
typedef __attribute__((ext_vector_type(4))) float f32x4;

// f32 -> bf16, round-to-nearest-even
__device__ __forceinline__ unsigned short f2bf(float f) {
    unsigned u = __builtin_bit_cast(unsigned, f);
    u += 0x7FFFu + ((u >> 16) & 1u);
    return (unsigned short)(u >> 16);
}
__device__ __forceinline__ float bf2f(unsigned short b) {
    return __builtin_bit_cast(float, (unsigned)b << 16);
}

// One-time: zero stats+replicas, pack W and A into exact MFMA fragment layout.
__global__ __launch_bounds__(512) void prep_pack(const float* __restrict__ A,
                                                 const float* __restrict__ W,
                                                 float* __restrict__ ws) {
    const int i = blockIdx.x * 512 + threadIdx.x;  // grid 4 -> 2048 threads
    for (int j = i; j < REP_OFF + NREP * 128; j += 2048) ws[j] = 0.0f;
    unsigned short* Wpk = reinterpret_cast<unsigned short*>(ws + WPK_OFF);
    unsigned short* Apk = reinterpret_cast<unsigned short*>(ws + APK_OFF);
    if (i < 1536) {
        // Wpk[mt][kap][lane]: A-operand frag, row o = mt*16+li, k-elems = kap*32+g*8+e
        int mt = i / 384, r = i - mt * 384;
        int kap = r / 64, lane = r - kap * 64;
        int li = lane & 15, g = lane >> 4;
        int o  = mt * 16 + li;
        int k  = kap >> 1, c0 = (kap & 1) * 32 + g * 8;
        const float* wp = W + ((size_t)(k * OO + o)) * CC + c0;
#pragma unroll
        for (int e = 0; e < 8; ++e) Wpk[i * 8 + e] = f2bf(wp[e]);
    } else if (i < 1920) {
        // Apk[k*2+nt][lane]: B-operand frag (A^T), col w = nt*16+li, k-elems v = g*8+e
        int j = i - 1536;
        int k = j / 128, r = j - k * 128;
        int nt = r / 64, lane = r - nt * 64;
        int li = lane & 15, g = lane >> 4;
        int w = nt * 16 + li;
#pragma unroll
        for (int e = 0; e < 8; ++e) {
            int v = g * 8 + e;
            float val = (v < VV && w < VV) ? A[(k * VV + v) * VV + w] : 0.0f;
            Apk[j * 8 + e] = f2bf(val);
        }
    }
}

// Block: (n, 2 time steps), 512 threads = 8 waves. R6-style 2-barrier schedule
// (R8's K-sliced 6-barrier variant regressed 54->73us: tiny C_k phases exposed
// Wpk load latency between barriers).
//  Phase A: stage x -> bf16 x_s[row=t*64+c][v pad32]  (8 KB)
//  Phase B: GEMM1 all k: xa_s[s=t*25+w][kc=k*64+c]    (24 KB)
//  Phase C: GEMM2 K=192 -> yac, epilogue stores + fused stats
template <int BF16Y>
__global__ __launch_bounds__(512, 6) void gcn_main(const float* __restrict__ x,
                                                   float* __restrict__ ws,
                                                   float* __restrict__ ypre) {
    __shared__ alignas(16) unsigned short x_s[128 * 32];   // 8 KB
    __shared__ alignas(16) unsigned short xa_s[64 * 192];  // 24 KB (rows 50..63 pad,
                                                           // feed masked-out C cols only)
    __shared__ float stats_s[128];

    const int bid  = blockIdx.x;
    const int n    = bid / (TT / TB);
    const int t0   = (bid % (TT / TB)) * TB;
    const int tid  = threadIdx.x;
    const int lane = tid & 63;
    const int wid  = tid >> 6;
    const int li   = lane & 15;   // fragment row/col index
    const int g    = lane >> 4;   // 16-lane group: k-elems = 8g..8g+7

    const short8* Wpk = reinterpret_cast<const short8*>(ws + WPK_OFF);
    const short8* Apk = reinterpret_cast<const short8*>(ws + APK_OFF);

    if (tid < 128) stats_s[tid] = 0.0f;

    // ---- Phase A: stage x[n,:,t0:t0+2,:] (float2 global loads: 50 floats/channel)
    const float* xg = x + (size_t)n * (CC * TT * VV) + (size_t)t0 * VV;
    for (int idx = tid; idx < CC * 25; idx += 512) {  // 1600 float2
        int c = idx / 25, q = idx - c * 25;
        const float2 f = *reinterpret_cast<const float2*>(xg + (size_t)c * (TT * VV) + q * 2);
        float vals[2] = {f.x, f.y};
        int s0 = q * 2;
#pragma unroll
        for (int i = 0; i < 2; ++i) {
            int sp = s0 + i;               // may straddle the 25-joint boundary
            int t = sp >= 25 ? 1 : 0, v = sp - t * 25;
            int row = t * 64 + c;
            x_s[row * 32 + (v ^ (((row >> 1) & 3) << 3))] = f2bf(vals[i]);
        }
    }
    for (int idx = tid; idx < 128 * 7; idx += 512) {  // zero-fill K-pad v=25..31
        int row = idx / 7, v = 25 + (idx - row * 7);
        x_s[row * 32 + (v ^ (((row >> 1) & 3) << 3))] = 0;
    }

    // ---- A^T B-fragments: 6 coalesced 16B loads (pre-packed)
    short8 afrag[6];
#pragma unroll
    for (int kn = 0; kn < 6; ++kn)
        afrag[kn] = *reinterpret_cast<const short8*>(
            reinterpret_cast<const unsigned short*>(Apk) + ((size_t)kn * 64 + lane) * 8);

    __syncthreads();

    // ---- Phase B: GEMM1. M=(t*64+c) 128 rows = 8 Mtiles (1/wave), N=w (2 tiles), K=32
    {
        const int row = wid * 16 + li;
        const short8 xf = *reinterpret_cast<const short8*>(
            &x_s[row * 32 + ((g * 8) ^ (((row >> 1) & 3) << 3))]);
        const int r0 = wid * 16 + g * 4;
        const int t = r0 >> 6, c0 = r0 & 63;
#pragma unroll
        for (int k = 0; k < KK; ++k) {
            f32x4 a0 = {0.f,0.f,0.f,0.f}, a1 = {0.f,0.f,0.f,0.f};
            a0 = __builtin_amdgcn_mfma_f32_16x16x32_bf16(xf, afrag[k * 2 + 0], a0, 0, 0, 0);
            a1 = __builtin_amdgcn_mfma_f32_16x16x32_bf16(xf, afrag[k * 2 + 1], a1, 0, 0, 0);
            int kc = k * 64 + c0;
            {
                int s = t * 25 + li;
                unsigned long long p =
                    (unsigned long long)f2bf(a0[0]) |
                    ((unsigned long long)f2bf(a0[1]) << 16) |
                    ((unsigned long long)f2bf(a0[2]) << 32) |
                    ((unsigned long long)f2bf(a0[3]) << 48);
                *reinterpret_cast<unsigned long long*>(
                    &xa_s[s * 192 + (kc ^ ((s & 7) << 3))]) = p;
            }
            int w1 = 16 + li;
            if (w1 < VV) {
                int s = t * 25 + w1;
                unsigned long long p =
                    (unsigned long long)f2bf(a1[0]) |
                    ((unsigned long long)f2bf(a1[1]) << 16) |
                    ((unsigned long long)f2bf(a1[2]) << 32) |
                    ((unsigned long long)f2bf(a1[3]) << 48);
                *reinterpret_cast<unsigned long long*>(
                    &xa_s[s * 192 + (kc ^ ((s & 7) << 3))]) = p;
            }
        }
    }
    __syncthreads();

    // ---- Phase C: GEMM2. M=o (4 Mtiles), N=s (4 Ntiles, last ragged), K=192 (6 MFMA)
    f32x4 yac[2];
#pragma unroll
    for (int i = 0; i < 2; ++i) {
        int u = wid + 8 * i;          // 0..15
        int mt = u >> 2, nt = u & 3;
        int srow = nt * 16 + li;
        const short8* wb = Wpk + (size_t)(mt * 6) * 64 + lane;
        f32x4 y = {0.f,0.f,0.f,0.f};
#pragma unroll
        for (int kap = 0; kap < 6; ++kap) {
            const short8 wf  = wb[(size_t)kap * 64];
            const short8 xaf = *reinterpret_cast<const short8*>(
                &xa_s[srow * 192 + ((kap * 32 + g * 8) ^ ((srow & 7) << 3))]);
            y = __builtin_amdgcn_mfma_f32_16x16x32_bf16(wf, xaf, y, 0, 0, 0);
        }
        yac[i] = y;
    }

    // ---- Epilogue: stores (f32 to ypre OR bf16 to ws) + fused per-channel stats
    unsigned short* ybf = reinterpret_cast<unsigned short*>(ws + YBF_OFF);
#pragma unroll
    for (int i = 0; i < 2; ++i) {
        int u = wid + 8 * i;
        int mt = u >> 2, nt = u & 3;
        int srow = nt * 16 + li;
        bool sv = srow < SB;
        int oq = mt * 16 + g * 4;
        size_t base = ((size_t)n * OO + oq) * (TT * VV) + (size_t)t0 * VV + srow;
        float s1[4], s2[4];
#pragma unroll
        for (int j = 0; j < 4; ++j) {
            float v = sv ? yac[i][j] : 0.0f;
            float vq;
            if (BF16Y) {
                unsigned short b = f2bf(v);
                vq = bf2f(b);                 // stats on quantized values (consistent BN)
                if (sv) ybf[base + (size_t)j * (TT * VV)] = b;
            } else {
                vq = v;
                if (sv) ypre[base + (size_t)j * (TT * VV)] = v;
            }
            s1[j] = vq;
            s2[j] = vq * vq;
        }
#pragma unroll
        for (int d = 1; d < 16; d <<= 1) {
#pragma unroll
            for (int j = 0; j < 4; ++j) {
                s1[j] += __shfl_xor(s1[j], d);
                s2[j] += __shfl_xor(s2[j], d);
            }
        }
        if (li == 0) {
#pragma unroll
            for (int j = 0; j < 4; ++j) {
                atomicAdd(&stats_s[oq + j], s1[j]);
                atomicAdd(&stats_s[64 + oq + j], s2[j]);
            }
        }
    }
    // NOTE: per-branch bias b.sum(0) is a per-channel constant -> exactly
    // cancelled by training-mode BN. Skipped on purpose (exact).
    __syncthreads();
    if (tid < 128)
        atomicAdd(&ws[REP_OFF + (bid & (NREP - 1)) * 128 + tid], stats_s[tid]);
}

// Fold NREP replicas -> final stats at ws[0..128)
__global__ __launch_bounds__(128) void reduce_stats(float* ws) {
    const int t = threadIdx.x;
    float s = 0.0f;
#pragma unroll 8
    for (int r = 0; r < NREP; ++r) s += ws[REP_OFF + r * 128 + t];
    ws[t] = s;
}

__global__ __launch_bounds__(256) void bn_relu_f32(float* __restrict__ y,
                                                   const float* __restrict__ stats,
                                                   const float* __restrict__ gamma,
                                                   const float* __restrict__ beta) {
    const int i4 = blockIdx.x * 256 + threadIdx.x;
    const size_t i = (size_t)i4 * 4;
    const int o = (int)((i / (TT * VV)) % OO);  // TT*VV=7500 divisible by 4

    const float cnt  = (float)NN * TT * VV;
    const float mean = stats[o] / cnt;
    const float var  = stats[OO + o] / cnt - mean * mean;
    const float inv  = rsqrtf(var + 1e-5f);
    const float sc   = gamma[o] * inv;
    const float sh   = beta[o] - mean * sc;

    float4 v = *reinterpret_cast<float4*>(y + i);
    v.x = fmaxf(v.x * sc + sh, 0.0f);
    v.y = fmaxf(v.y * sc + sh, 0.0f);
    v.z = fmaxf(v.z * sc + sh, 0.0f);
    v.w = fmaxf(v.w * sc + sh, 0.0f);
    *reinterpret_cast<float4*>(y + i) = v;
}

__global__ __launch_bounds__(256) void bn_relu_bf(float* __restrict__ out,
                                                  const float* __restrict__ ws,
                                                  const float* __restrict__ gamma,
                                                  const float* __restrict__ beta) {
    const int i4 = blockIdx.x * 256 + threadIdx.x;
    const size_t i = (size_t)i4 * 4;
    const int o = (int)((i / (TT * VV)) % OO);

    const float cnt  = (float)NN * TT * VV;
    const float mean = ws[o] / cnt;
    const float var  = ws[OO + o] / cnt - mean * mean;
    const float inv  = rsqrtf(var + 1e-5f);
    const float sc   = gamma[o] * inv;
    const float sh   = beta[o] - mean * sc;

    const ushort4 u = *reinterpret_cast<const ushort4*>(
        reinterpret_cast<const unsigned short*>(ws + YBF_OFF) + i);
    float4 v;
    v.x = fmaxf(bf2f(u.x) * sc + sh, 0.0f);
    v.y = fmaxf(bf2f(u.y) * sc + sh, 0.0f);
    v.z = fmaxf(bf2f(u.z) * sc + sh, 0.0f);
    v.w = fmaxf(bf2f(u.w) * sc + sh, 0.0f);
    *reinterpret_cast<float4*>(out + i) = v;
}

extern "C" void kernel_launch(void* const* d_in, const int* in_sizes, int n_in,
                              void* d_out, int out_size, void* d_ws, size_t ws_size,
                              hipStream_t stream) {
    const float* x     = (const float*)d_in[0];
    const float* A     = (const float*)d_in[1];
    const float* W     = (const float*)d_in[2];
    // d_in[3] = b : exactly cancelled by training-mode BN, unused
    const float* gamma = (const float*)d_in[4];
    const float* beta  = (const float*)d_in[5];
    float* out = (float*)d_out;
    float* ws  = (float*)d_ws;

    const bool bf16y = ws_size >= WS_NEED_BF16;  // host-side, deterministic

    hipLaunchKernelGGL(prep_pack, dim3(4), dim3(512), 0, stream, A, W, ws);
    if (bf16y) {
        hipLaunchKernelGGL(HIP_KERNEL_NAME(gcn_main<1>), dim3(NN * (TT / TB)), dim3(512),
                           0, stream, x, ws, out);
        hipLaunchKernelGGL(reduce_stats, dim3(1), dim3(128), 0, stream, ws);
        hipLaunchKernelGGL(bn_relu_bf, dim3((NN * OO * TT * VV) / 4 / 256), dim3(256),
                           0, stream, out, ws, gamma, beta);
    } else {
        hipLaunchKernelGGL(HIP_KERNEL_NAME(gcn_main<0>), dim3(NN * (TT / TB)), dim3(512),
                           0, stream, x, ws, out);
        hipLaunchKernelGGL(reduce_stats, dim3(1), dim3(128), 0, stream, ws);
        hipLaunchKernelGGL(bn_relu_f32, dim3((NN * OO * TT * VV) / 4 / 256), dim3(256),
                           0, stream, out, ws, gamma, beta);
    }
}